// Round 18
// baseline (150.122 us; speedup 1.0000x reference)
//
#include <hip/hip_runtime.h>
#include <math.h>

#define NSLOT 256
#define HWN   16384
#define D_    256
#define BB    4
#define NSEL  768
#define NPOS  512
#define NHEAD 8
#define SEGS  20                         // topk candidate capacity = 20*64 = 1280

typedef __attribute__((ext_vector_type(8))) short short8v;   // 8 bf16 (4 VGPRs)
typedef __attribute__((ext_vector_type(4))) float float4v;   // MFMA C/D

// global->LDS DMA: 16B per lane; LDS dest wave-uniform base; GLOBAL SOURCE PER-LANE.
#define GLD16(g, l)                                                        \
  __builtin_amdgcn_global_load_lds(                                        \
      (__attribute__((address_space(1))) void*)(g),                        \
      (__attribute__((address_space(3))) void*)(l), 16, 0, 0)

#define BFLO(u) __uint_as_float((u) << 16)
#define BFHI(u) __uint_as_float((u) & 0xffff0000u)

__device__ __forceinline__ unsigned short f2bf(float x) {   // RNE bf16
  unsigned u = __float_as_uint(x);
  unsigned r = u + 0x7fffu + ((u >> 16) & 1u);
  return (unsigned short)(r >> 16);
}
__device__ __forceinline__ unsigned int pk2(float a, float b) {
  return (unsigned)f2bf(a) | ((unsigned)f2bf(b) << 16);
}

// ---------------- Kernel PREP, grid=512 (exactly 2 blocks/CU -> all co-resident):
//   blocks 0-255:  topk(slot B) then qproj(slot B) sequentially in-block
//   blocks 256-511: pack (8 grid-strided iters/thread)
// R17 lesson: 832 blocks @1024thr = 512 resident + 320 serialized after topk.
union PrepSmem {
  struct {
    unsigned int hist[4096];
    unsigned int wsum[16];
    unsigned long long skey[SEGS * 64];
    int sBstar;
    unsigned int sCount;
  } tk;                                   // ~26.7 KB
  struct {
    float srow[D_];
    float qrow[D_];
    float qkl[NHEAD][D_];
    float qsl[D_];
    float pq[1024];
  } qp;                                   // ~15.4 KB
};

__global__ __launch_bounds__(1024) void prep_kernel(
    const float* __restrict__ curio, int* __restrict__ feat_sel,
    const float* __restrict__ slots, const float* __restrict__ ipw,
    const float* __restrict__ ipb, float* __restrict__ qbk_g,
    unsigned short* __restrict__ qkb16,
    const float* __restrict__ fsrc, const float* __restrict__ psrc,
    unsigned short* __restrict__ kpf) {
  __shared__ PrepSmem sm;
  int B = blockIdx.x;
  int t = threadIdx.x;

  if (B < 256) {
    // ================= phase 1: topk (slot B) =================
    int s = B;
    int wave = t >> 6, lane = t & 63;
    const float* row = curio + (size_t)s * HWN;

    for (int i = t; i < 4096; i += 1024) sm.tk.hist[i] = 0;
    if (t == 0) sm.tk.sCount = 0;
    __syncthreads();
    for (int j = t; j < HWN; j += 1024) {
      unsigned int bits = __float_as_uint(row[j]);   // values in [0,1): bits monotone
      atomicAdd(&sm.tk.hist[bits >> 18], 1u);
    }
    __syncthreads();
    unsigned int cs = sm.tk.hist[t * 4] + sm.tk.hist[t * 4 + 1] +
                      sm.tk.hist[t * 4 + 2] + sm.tk.hist[t * 4 + 3];
    unsigned int v = cs;
#pragma unroll
    for (int off = 1; off < 64; off <<= 1) {
      unsigned int u = __shfl_down(v, off, 64);
      if (lane + off < 64) v += u;       // suffix over lanes >= lane (this wave)
    }
    if (lane == 0) sm.tk.wsum[wave] = v;
    __syncthreads();
    unsigned int above = 0;
    for (int w2 = wave + 1; w2 < 16; w2++) above += sm.tk.wsum[w2];
    unsigned int sufAfter = above + (v - cs);
    if (sufAfter < NSEL && sufAfter + cs >= NSEL) {
      unsigned int local = sufAfter;
      for (int b2 = t * 4 + 3; b2 >= t * 4; b2--) {
        unsigned int c = sm.tk.hist[b2];
        if (local + c >= NSEL) { sm.tk.sBstar = b2; break; }
        local += c;
      }
    }
    __syncthreads();
    int bstar = sm.tk.sBstar;
    // collect candidates: one atomic per wave-iteration (ballot aggregation)
    for (int j = t; j < HWN; j += 1024) {
      unsigned int bits = __float_as_uint(row[j]);
      bool cand = ((int)(bits >> 18) >= bstar);
      unsigned long long mask = __ballot(cand);
      unsigned int base = 0;
      int lcnt = __popcll(mask);
      if (lane == 0 && lcnt) base = atomicAdd(&sm.tk.sCount, (unsigned)lcnt);
      base = __shfl(base, 0, 64);
      if (cand) {
        unsigned pos = base + __popcll(mask & ((1ull << lane) - 1ull));
        if (pos < SEGS * 64)
          sm.tk.skey[pos] = ((unsigned long long)bits << 14) |
                            (unsigned long long)(16383 - j);
      }
    }
    __syncthreads();
    unsigned int M = sm.tk.sCount;
    if (M > SEGS * 64) M = SEGS * 64;
    for (int i = t; i < SEGS * 64; i += 1024) if (i >= (int)M) sm.tk.skey[i] = 0ull;
    __syncthreads();
    // wave-local bitonic sort (descending) of each 64-seg, pure shuffles
    for (int seg = wave; seg < SEGS; seg += 16) {
      unsigned long long kv = sm.tk.skey[seg * 64 + lane];
#pragma unroll
      for (int k = 2; k <= 64; k <<= 1) {
#pragma unroll
        for (int j2 = k >> 1; j2 > 0; j2 >>= 1) {
          unsigned long long o = __shfl_xor(kv, j2, 64);
          bool lower = ((lane & j2) == 0);
          bool descblk = ((lane & k) == 0);
          bool wantmax = (descblk == lower);
          kv = (wantmax == (kv >= o)) ? kv : o;
        }
      }
      sm.tk.skey[seg * 64 + lane] = kv;
    }
    __syncthreads();
    // merge-rank: rank = pos-in-own-seg + sum over other segs of count(> key)
    for (int e = t; e < SEGS * 64; e += 1024) {
      unsigned long long key = sm.tk.skey[e];
      if (key == 0ull) continue;  // padding
      int seg = e >> 6;
      int rank = e & 63;
      for (int g = 0; g < SEGS; g++) {
        if (g == seg) continue;
        const unsigned long long* sp = &sm.tk.skey[g * 64];
        int lo = 0, hi = 64;
        while (lo < hi) {
          int mid = (lo + hi) >> 1;
          if (sp[mid] > key) lo = mid + 1; else hi = mid;
        }
        rank += lo;
      }
      if (rank < NSEL) feat_sel[s * NSEL + rank] = 16383 - (int)(key & 16383ull);
    }
    __syncthreads();   // topk done; LDS union reused below

    // ================= phase 2: qproj (slot B), all 1024 threads =================
    if (t < 256) sm.qp.srow[t] = slots[s * D_ + t];
    __syncthreads();
    {
      int o = t >> 2, part = t & 3;
      const float4* w4 = (const float4*)(ipw + (size_t)o * D_ + part * 64);
      float a = 0.f;
#pragma unroll
      for (int i = 0; i < 16; i++) {
        float4 w = w4[i];
        int d = part * 64 + i * 4;
        a += sm.qp.srow[d] * w.x + sm.qp.srow[d + 1] * w.y +
             sm.qp.srow[d + 2] * w.z + sm.qp.srow[d + 3] * w.w;
      }
      sm.qp.pq[t] = a;
    }
    __syncthreads();
    if (t < 256)
      sm.qp.qrow[t] = (sm.qp.pq[t * 4] + sm.qp.pq[t * 4 + 1] + sm.qp.pq[t * 4 + 2] +
                       sm.qp.pq[t * 4 + 3] + ipb[t]) * 0.17677669529663689f;
    __syncthreads();
    // qk[h][c]: 2048 dot-32s over 1024 threads (2 each)
    for (int e = t; e < 2048; e += 1024) {
      int h = e >> 8, c = e & 255;
      const float* wk = ipw + (size_t)(D_ + h * 32) * D_ + c;
      float a = 0.f;
#pragma unroll
      for (int k = 0; k < 32; k++) a += sm.qp.qrow[h * 32 + k] * wk[(size_t)k * D_];
      sm.qp.qkl[h][c] = a;
    }
    __syncthreads();
    if (t < 256) {
      float qs = 0.f;
#pragma unroll
      for (int h = 0; h < NHEAD; h++) qs += sm.qp.qkl[h][t];
      sm.qp.qsl[t] = qs;
    }
    if (t < NHEAD) {
      float a = 0.f;
      for (int e = 0; e < 32; e++) a += sm.qp.qrow[t * 32 + e] * ipb[D_ + t * 32 + e];
      qbk_g[s * NHEAD + t] = a;
    }
    __syncthreads();
    // qkb16[s][e], e=((kc*64+l)*8+j): col=l&15; k=kc*32+((l>>4)&3)*8+j.
    // cols 0-7 heads, col 8 qksum, 9-15 zero.
    for (int e = t; e < 4096; e += 1024) {
      int kc = e >> 9, l = (e >> 3) & 63, j = e & 7;
      int cc = l & 15, k = kc * 32 + ((l >> 4) & 3) * 8 + j;
      float v2 = (cc < NHEAD) ? sm.qp.qkl[cc][k] : ((cc == NHEAD) ? sm.qp.qsl[k] : 0.f);
      qkb16[(size_t)s * 4096 + e] = f2bf(v2);
    }
  } else {
    // ================= pack: kpf rows (1KB): [0:512) sigma-swizzled bf16(f+p),
    //                   [512:1024) linear bf16(f). 8 iters/thread. =================
    int stride = 256 * 1024;
#pragma unroll 2
    for (int u = (B - 256) * 1024 + t; u < HWN * BB * 32; u += stride) {
      int row = u >> 5, b2 = u & 31;
      int c8 = b2 << 3;
      const float4* f4 = (const float4*)(fsrc + (size_t)row * D_ + c8);
      const float4* p4 = (const float4*)(psrc + (size_t)row * D_ + c8);
      float4 a0 = f4[0], a1 = f4[1], b0 = p4[0], b1 = p4[1];
      uint4 kp, ff;
      kp.x = pk2(a0.x + b0.x, a0.y + b0.y);
      kp.y = pk2(a0.z + b0.z, a0.w + b0.w);
      kp.z = pk2(a1.x + b1.x, a1.y + b1.y);
      kp.w = pk2(a1.z + b1.z, a1.w + b1.w);
      ff.x = pk2(a0.x, a0.y); ff.y = pk2(a0.z, a0.w);
      ff.z = pk2(a1.x, a1.y); ff.w = pk2(a1.z, a1.w);
      int sig = row & 7;
      *(uint4*)(kpf + (size_t)row * 512 + ((b2 ^ sig) << 3)) = kp;
      *(uint4*)(kpf + (size_t)row * 512 + 256 + c8) = ff;
    }
  }
}

// ---------------- Kernel C (MFMA): aff via matrix cores + scalar PV (R15-R17, passing) ----------------
__global__ __launch_bounds__(256, 3) void aff_pv_mfma_kernel(
    const unsigned short* __restrict__ kpf,
    const unsigned short* __restrict__ qkb16,
    const int* __restrict__ batch_idx, const int* __restrict__ feat_sel,
    const float* __restrict__ qbk_g,
    float* __restrict__ fbar_part,    // [256][2][8][256]
    float* __restrict__ expsum_part,  // [256][2][8]
    float* __restrict__ stat_part,    // [256][2][2]
    float* __restrict__ aff2_g) {     // [256][768]
  __shared__ unsigned short kplds[4][4096];     // 32 KB: per-wave 16 rows x 512B (sigma layout)
  __shared__ unsigned short qkb[4096];          // 8 KB
  __shared__ float wlds[4][16][17];             // 4.3 KB
  __shared__ float fbar[NHEAD][D_];             // 8 KB
  __shared__ float a2buf[384];
  __shared__ int   sfsel[384];
  __shared__ float esums[4][NHEAD];
  __shared__ float sstat[4][2];
  __shared__ float qbkmean_s;

  int b = blockIdx.x, s = b >> 1, half = b & 1;
  int t = threadIdx.x, w = t >> 6, lane = t & 63;
  int bi = batch_idx[s];
  int col = lane & 15, quad = lane >> 4;

  {
    const uint4* src = (const uint4*)(qkb16 + (size_t)s * 4096);
    ((uint4*)qkb)[t] = src[t];
    ((uint4*)qkb)[t + 256] = src[t + 256];
  }
  for (int i = t; i < 384; i += 256) sfsel[i] = feat_sel[s * NSEL + half + 2 * i];
  for (int i = t; i < NHEAD * D_; i += 256) ((float*)fbar)[i] = 0.f;
  if (t == 0) {
    float m = 0.f;
    for (int h = 0; h < NHEAD; h++) m += qbk_g[s * NHEAD + h];
    qbkmean_s = m * 0.125f;
  }
  __syncthreads();

  unsigned short* kslot = &kplds[w][0];
  float acc[NHEAD][4];
#pragma unroll
  for (int h = 0; h < NHEAD; h++)
#pragma unroll
    for (int c = 0; c < 4; c++) acc[h][c] = 0.f;
  float esum_acc = 0.f;  // valid on lanes with col<8 (head=col)

  // 8 paired GLD16: lanes 0-31 <- row 2p kp-half, lanes 32-63 <- row 2p+1 kp-half.
  auto ISSUE_KP = [&](int L) {
#pragma unroll
    for (int p = 0; p < 8; p++) {
      int r0 = sfsel[L + 2 * p], r1 = sfsel[L + 2 * p + 1];
      unsigned ridx = (unsigned)((lane < 32 ? r0 : r1) * BB + bi);
      const unsigned short* src = kpf + (size_t)ridx * 512 + (lane & 31) * 8;
      GLD16(src, kslot + p * 512);
    }
  };

  ISSUE_KP(w * 64);  // prologue: tile 0
#pragma unroll 1
  for (int i = 0; i < 6; i++) {
    int L = (i < 4) ? (w * 64 + i * 16) : (256 + w * 32 + (i - 4) * 16);
    asm volatile("s_waitcnt vmcnt(0)" ::: "memory");  // tile i's 8 DMAs landed
    bool pos = (i < 4);
    uint2 fu[16];
    if (pos) {
#pragma unroll
      for (int r = 0; r < 16; r++)
        fu[r] = *(const uint2*)(kpf + (size_t)((unsigned)sfsel[L + r] * BB + bi) * 512 +
                                256 + lane * 4);
    }
    // A-frags: row col, k-block (kc*4+quad) xor sigma(row)
    unsigned sig = ((unsigned)sfsel[L + col] * BB + bi) & 7u;
    short8v afr[8];
#pragma unroll
    for (int kc = 0; kc < 8; kc++) {
      unsigned blk = ((unsigned)(kc * 4 + quad)) ^ sig;
      afr[kc] = *(const short8v*)(kslot + col * 256 + blk * 8);
    }
    asm volatile("s_waitcnt lgkmcnt(0)" ::: "memory");  // A reads done before slot reuse
    __builtin_amdgcn_sched_barrier(0);
    if (i < 5) {
      int Ln = (i < 3) ? (w * 64 + (i + 1) * 16) : (256 + w * 32 + (i - 3) * 16);
      ISSUE_KP(Ln);
    }
    float4v c = {0.f, 0.f, 0.f, 0.f};
#pragma unroll
    for (int kc = 0; kc < 8; kc++) {
      short8v bfr = *(const short8v*)&qkb[(kc * 64 + lane) * 8];
      c = __builtin_amdgcn_mfma_f32_16x16x32_bf16(afr[kc], bfr, c, 0, 0, 0);
    }
    // C: row n = quad*4+j (local row L+n), col: 0-7 heads, 8 = qksum-dot
    if (pos) {
      if (col < NHEAD) {
        float e0 = __expf(c[0]), e1 = __expf(c[1]), e2 = __expf(c[2]), e3 = __expf(c[3]);
        esum_acc += e0 + e1 + e2 + e3;
        wlds[w][quad * 4 + 0][col] = e0;
        wlds[w][quad * 4 + 1][col] = e1;
        wlds[w][quad * 4 + 2][col] = e2;
        wlds[w][quad * 4 + 3][col] = e3;
      } else if (col == NHEAD) {
        float qm = qbkmean_s;
#pragma unroll
        for (int j = 0; j < 4; j++) a2buf[L + quad * 4 + j] = c[j] * 0.125f + qm;
      }
      asm volatile("s_waitcnt lgkmcnt(0)" ::: "memory");  // wlds writes visible in-wave
      __builtin_amdgcn_sched_barrier(0);
#pragma unroll
      for (int r = 0; r < 16; r++) {
        const float4 w0 = *(const float4*)&wlds[w][r][0];
        const float4 w1 = *(const float4*)&wlds[w][r][4];
        float f0 = BFLO(fu[r].x), f1 = BFHI(fu[r].x), f2 = BFLO(fu[r].y), f3 = BFHI(fu[r].y);
        acc[0][0] += w0.x * f0; acc[0][1] += w0.x * f1; acc[0][2] += w0.x * f2; acc[0][3] += w0.x * f3;
        acc[1][0] += w0.y * f0; acc[1][1] += w0.y * f1; acc[1][2] += w0.y * f2; acc[1][3] += w0.y * f3;
        acc[2][0] += w0.z * f0; acc[2][1] += w0.z * f1; acc[2][2] += w0.z * f2; acc[2][3] += w0.z * f3;
        acc[3][0] += w0.w * f0; acc[3][1] += w0.w * f1; acc[3][2] += w0.w * f2; acc[3][3] += w0.w * f3;
        acc[4][0] += w1.x * f0; acc[4][1] += w1.x * f1; acc[4][2] += w1.x * f2; acc[4][3] += w1.x * f3;
        acc[5][0] += w1.y * f0; acc[5][1] += w1.y * f1; acc[5][2] += w1.y * f2; acc[5][3] += w1.y * f3;
        acc[6][0] += w1.z * f0; acc[6][1] += w1.z * f1; acc[6][2] += w1.z * f2; acc[6][3] += w1.z * f3;
        acc[7][0] += w1.w * f0; acc[7][1] += w1.w * f1; acc[7][2] += w1.w * f2; acc[7][3] += w1.w * f3;
      }
    } else {
      if (col == NHEAD) {
        float qm = qbkmean_s;
#pragma unroll
        for (int j = 0; j < 4; j++) a2buf[L + quad * 4 + j] = c[j] * 0.125f + qm;
      }
    }
  }

  // esum: combine quads (lanes h, h+16, h+32, h+48 all have col==h for h<8)
  esum_acc += __shfl_xor(esum_acc, 16, 64);
  esum_acc += __shfl_xor(esum_acc, 32, 64);
  if (lane < NHEAD) esums[w][lane] = esum_acc;
#pragma unroll
  for (int h = 0; h < NHEAD; h++) {
    atomicAdd(&fbar[h][lane * 4 + 0], acc[h][0]);
    atomicAdd(&fbar[h][lane * 4 + 1], acc[h][1]);
    atomicAdd(&fbar[h][lane * 4 + 2], acc[h][2]);
    atomicAdd(&fbar[h][lane * 4 + 3], acc[h][3]);
  }
  __syncthreads();

  {
    float v1 = a2buf[t];
    float v2 = (t < 128) ? a2buf[256 + t] : 0.f;
    float ls = v1 + v2, lq = v1 * v1 + v2 * v2;
#pragma unroll
    for (int off = 32; off >= 1; off >>= 1) { ls += __shfl_xor(ls, off, 64); lq += __shfl_xor(lq, off, 64); }
    if (lane == 0) { sstat[w][0] = ls; sstat[w][1] = lq; }
  }
  __syncthreads();
  if (t < NHEAD) {
    expsum_part[b * NHEAD + t] = esums[0][t] + esums[1][t] + esums[2][t] + esums[3][t];
  } else if (t == NHEAD) {
    stat_part[b * 2 + 0] = sstat[0][0] + sstat[1][0] + sstat[2][0] + sstat[3][0];
    stat_part[b * 2 + 1] = sstat[0][1] + sstat[1][1] + sstat[2][1] + sstat[3][1];
  }
  aff2_g[s * NSEL + half + 2 * t] = a2buf[t];
  if (t < 128) aff2_g[s * NSEL + half + 2 * (256 + t)] = a2buf[256 + t];
  ((float4*)(fbar_part + (size_t)b * 2048))[t] = ((float4*)fbar)[t];
  ((float4*)(fbar_part + (size_t)b * 2048))[t + 256] = ((float4*)fbar)[t + 256];
}

// ---------------- Kernel D: combine partials + Wv + out-proj + LN + norm_aff ----------------
__global__ __launch_bounds__(1024) void finish_kernel(
    const float* __restrict__ slots,
    const float* __restrict__ expsum_part, const float* __restrict__ stat_part,
    const float* __restrict__ aff2_g, const float* __restrict__ fbar_part,
    const float* __restrict__ ipw, const float* __restrict__ ipb,
    const float* __restrict__ wout, const float* __restrict__ bout,
    const float* __restrict__ lnw, const float* __restrict__ lnb,
    float* __restrict__ slots_new, float* __restrict__ norm_aff) {
  __shared__ float fbar[NHEAD][D_];
  __shared__ float srow[D_];
  __shared__ float outv[D_];
  __shared__ float pq[1024];
  __shared__ float redS[4], redQ[4];
  int s = blockIdx.x, t = threadIdx.x, wave = t >> 6, lane = t & 63;

  float st0 = stat_part[s * 4 + 0] + stat_part[s * 4 + 2];
  float st1 = stat_part[s * 4 + 1] + stat_part[s * 4 + 3];
  float mean_a = st0 * (1.0f / NSEL);
  float var_a = st1 * (1.0f / NSEL) - mean_a * mean_a;
  float rstd_a = rsqrtf(var_a + 1e-5f);
  if (t < NSEL) norm_aff[(size_t)t * NSLOT + s] = (aff2_g[s * NSEL + t] - mean_a) * rstd_a;

  if (t < 512) {
    int h = t >> 6;  // fbar layout [8][256]: 64 float4s per head
    float inv = 1.0f / (expsum_part[s * 16 + h] + expsum_part[s * 16 + 8 + h]);
    const float4 a = ((const float4*)(fbar_part + (size_t)s * 4096))[t];
    const float4 c = ((const float4*)(fbar_part + (size_t)s * 4096 + 2048))[t];
    float4 r;
    r.x = (a.x + c.x) * inv; r.y = (a.y + c.y) * inv;
    r.z = (a.z + c.z) * inv; r.w = (a.w + c.w) * inv;
    ((float4*)fbar)[t] = r;
  }
  if (t < 64) ((float4*)srow)[t] = ((const float4*)(slots + (size_t)s * D_))[t];
  __syncthreads();

  {
    int o = t >> 2, part = t & 3, h = o >> 5;
    const float4* wv = (const float4*)(ipw + (size_t)(2 * D_ + o) * D_ + part * 64);
    float a = 0.f;
#pragma unroll
    for (int i = 0; i < 16; i++) {
      float4 w = wv[i];
      int d = part * 64 + i * 4;
      a += fbar[h][d] * w.x + fbar[h][d + 1] * w.y + fbar[h][d + 2] * w.z + fbar[h][d + 3] * w.w;
    }
    pq[t] = a;
  }
  __syncthreads();
  if (t < D_)
    outv[t] = pq[t * 4] + pq[t * 4 + 1] + pq[t * 4 + 2] + pq[t * 4 + 3] + ipb[2 * D_ + t];
  __syncthreads();

  {
    int o = t >> 2, part = t & 3;
    const float4* w4 = (const float4*)(wout + (size_t)o * D_ + part * 64);
    float a = 0.f;
#pragma unroll
    for (int i = 0; i < 16; i++) {
      float4 w = w4[i];
      int d = part * 64 + i * 4;
      a += outv[d] * w.x + outv[d + 1] * w.y + outv[d + 2] * w.z + outv[d + 3] * w.w;
    }
    pq[t] = a;
  }
  __syncthreads();
  float v = 0.f;
  if (t < D_) {
    v = srow[t] + pq[t * 4] + pq[t * 4 + 1] + pq[t * 4 + 2] + pq[t * 4 + 3] + bout[t];
    float ls = v, lq = v * v;
#pragma unroll
    for (int off = 32; off >= 1; off >>= 1) { ls += __shfl_xor(ls, off, 64); lq += __shfl_xor(lq, off, 64); }
    if (lane == 0) { redS[wave] = ls; redQ[wave] = lq; }
  }
  __syncthreads();
  if (t < D_) {
    float tots = redS[0] + redS[1] + redS[2] + redS[3];
    float totq = redQ[0] + redQ[1] + redQ[2] + redQ[3];
    float mean = tots * (1.0f / D_);
    float var = totq * (1.0f / D_) - mean * mean;
    float rstd = rsqrtf(var + 1e-5f);
    slots_new[s * D_ + t] = (v - mean) * rstd * lnw[t] + lnb[t];
  }
}

extern "C" void kernel_launch(void* const* d_in, const int* in_sizes, int n_in,
                              void* d_out, int out_size, void* d_ws, size_t ws_size,
                              hipStream_t stream) {
  const float* slots    = (const float*)d_in[0];
  const float* features = (const float*)d_in[1];
  const float* posenc   = (const float*)d_in[2];
  const float* curio    = (const float*)d_in[3];
  const int*   batch_idx= (const int*)d_in[4];
  const float* ipw      = (const float*)d_in[5];
  const float* ipb      = (const float*)d_in[6];
  const float* wout     = (const float*)d_in[7];
  const float* bout     = (const float*)d_in[8];
  const float* lnw      = (const float*)d_in[9];
  const float* lnb      = (const float*)d_in[10];

  char* ws = (char*)d_ws;
  size_t off = 0;
  int*   feat_sel    = (int*)(ws + off);   off += 256 * 768 * 4;        // 786432
  float* qbk_g       = (float*)(ws + off); off += 256 * 8 * 4;          // 8192
  unsigned short* qkb16 = (unsigned short*)(ws + off); off += 256 * 4096 * 2; // 2097152
  float* fbar_part   = (float*)(ws + off); off += 256 * 2 * 8 * 256 * 4;// 4194304
  float* expsum_part = (float*)(ws + off); off += 256 * 2 * 8 * 4;      // 16384
  float* stat_part   = (float*)(ws + off); off += 256 * 2 * 2 * 4;      // 4096
  float* aff2_g      = (float*)(ws + off); off += 256 * 768 * 4;        // 786432
  size_t kpf_off = (off + 1023) & ~(size_t)1023;
  unsigned short* kpf = (unsigned short*)(ws + kpf_off);                // 67108864

  float* out_f = (float*)d_out;  // [0,65536) slots_new, [65536,262144) norm_aff

  prep_kernel<<<512, 1024, 0, stream>>>(curio, feat_sel, slots, ipw, ipb,
                                        qbk_g, qkb16, features, posenc, kpf);
  aff_pv_mfma_kernel<<<NSLOT * 2, 256, 0, stream>>>(kpf, qkb16, batch_idx, feat_sel,
                                                    qbk_g, fbar_part, expsum_part,
                                                    stat_part, aff2_g);
  finish_kernel<<<NSLOT, 1024, 0, stream>>>(slots, expsum_part, stat_part, aff2_g,
                                            fbar_part, ipw, ipb, wout, bout, lnw, lnb,
                                            out_f, out_f + 65536);
}

// Round 19
// 144.462 us; speedup vs baseline: 1.0392x; 1.0392x over previous
//
#include <hip/hip_runtime.h>
#include <math.h>

#define NSLOT 256
#define HWN   16384
#define D_    256
#define BB    4
#define NSEL  768
#define NPOS  512
#define NHEAD 8
#define SEGS  20                         // topk candidate capacity = 20*64 = 1280
#define PACKB 576                        // pack block count (blocks 256..831)

typedef __attribute__((ext_vector_type(8))) short short8v;   // 8 bf16 (4 VGPRs)
typedef __attribute__((ext_vector_type(4))) float float4v;   // MFMA C/D

// global->LDS DMA: 16B per lane; LDS dest wave-uniform base; GLOBAL SOURCE PER-LANE.
#define GLD16(g, l)                                                        \
  __builtin_amdgcn_global_load_lds(                                        \
      (__attribute__((address_space(1))) void*)(g),                        \
      (__attribute__((address_space(3))) void*)(l), 16, 0, 0)

#define BFLO(u) __uint_as_float((u) << 16)
#define BFHI(u) __uint_as_float((u) & 0xffff0000u)

__device__ __forceinline__ unsigned short f2bf(float x) {   // RNE bf16
  unsigned u = __float_as_uint(x);
  unsigned r = u + 0x7fffu + ((u >> 16) & 1u);
  return (unsigned short)(r >> 16);
}
__device__ __forceinline__ unsigned int pk2(float a, float b) {
  return (unsigned)f2bf(a) | ((unsigned)f2bf(b) << 16);
}

// ---------------- Kernel PREP, grid=832:
//   blocks 0-255:  topk(slot B) then qproj(slot B) sequentially in-block (R18-validated)
//   blocks 256-831: pack, 576 blocks (R17-validated tail at 2 blocks/CU)
// R17/R18 lessons: pack tail needs 2 blocks/CU (R17 shape); qproj fusion frees 64
// block-slots for pack in the first residency wave (192 -> 256 pack blocks).
union PrepSmem {
  struct {
    unsigned int hist[4096];
    unsigned int wsum[16];
    unsigned long long skey[SEGS * 64];
    int sBstar;
    unsigned int sCount;
  } tk;                                   // ~26.7 KB
  struct {
    float srow[D_];
    float qrow[D_];
    float qkl[NHEAD][D_];
    float qsl[D_];
    float pq[1024];
  } qp;                                   // ~15.4 KB
};

__global__ __launch_bounds__(1024) void prep_kernel(
    const float* __restrict__ curio, int* __restrict__ feat_sel,
    const float* __restrict__ slots, const float* __restrict__ ipw,
    const float* __restrict__ ipb, float* __restrict__ qbk_g,
    unsigned short* __restrict__ qkb16,
    const float* __restrict__ fsrc, const float* __restrict__ psrc,
    unsigned short* __restrict__ kpf) {
  __shared__ PrepSmem sm;
  int B = blockIdx.x;
  int t = threadIdx.x;

  if (B < 256) {
    // ================= phase 1: topk (slot B) =================
    int s = B;
    int wave = t >> 6, lane = t & 63;
    const float* row = curio + (size_t)s * HWN;

    for (int i = t; i < 4096; i += 1024) sm.tk.hist[i] = 0;
    if (t == 0) sm.tk.sCount = 0;
    __syncthreads();
    for (int j = t; j < HWN; j += 1024) {
      unsigned int bits = __float_as_uint(row[j]);   // values in [0,1): bits monotone
      atomicAdd(&sm.tk.hist[bits >> 18], 1u);
    }
    __syncthreads();
    unsigned int cs = sm.tk.hist[t * 4] + sm.tk.hist[t * 4 + 1] +
                      sm.tk.hist[t * 4 + 2] + sm.tk.hist[t * 4 + 3];
    unsigned int v = cs;
#pragma unroll
    for (int off = 1; off < 64; off <<= 1) {
      unsigned int u = __shfl_down(v, off, 64);
      if (lane + off < 64) v += u;       // suffix over lanes >= lane (this wave)
    }
    if (lane == 0) sm.tk.wsum[wave] = v;
    __syncthreads();
    unsigned int above = 0;
    for (int w2 = wave + 1; w2 < 16; w2++) above += sm.tk.wsum[w2];
    unsigned int sufAfter = above + (v - cs);
    if (sufAfter < NSEL && sufAfter + cs >= NSEL) {
      unsigned int local = sufAfter;
      for (int b2 = t * 4 + 3; b2 >= t * 4; b2--) {
        unsigned int c = sm.tk.hist[b2];
        if (local + c >= NSEL) { sm.tk.sBstar = b2; break; }
        local += c;
      }
    }
    __syncthreads();
    int bstar = sm.tk.sBstar;
    // collect candidates: one atomic per wave-iteration (ballot aggregation)
    for (int j = t; j < HWN; j += 1024) {
      unsigned int bits = __float_as_uint(row[j]);
      bool cand = ((int)(bits >> 18) >= bstar);
      unsigned long long mask = __ballot(cand);
      unsigned int base = 0;
      int lcnt = __popcll(mask);
      if (lane == 0 && lcnt) base = atomicAdd(&sm.tk.sCount, (unsigned)lcnt);
      base = __shfl(base, 0, 64);
      if (cand) {
        unsigned pos = base + __popcll(mask & ((1ull << lane) - 1ull));
        if (pos < SEGS * 64)
          sm.tk.skey[pos] = ((unsigned long long)bits << 14) |
                            (unsigned long long)(16383 - j);
      }
    }
    __syncthreads();
    unsigned int M = sm.tk.sCount;
    if (M > SEGS * 64) M = SEGS * 64;
    for (int i = t; i < SEGS * 64; i += 1024) if (i >= (int)M) sm.tk.skey[i] = 0ull;
    __syncthreads();
    // wave-local bitonic sort (descending) of each 64-seg, pure shuffles
    for (int seg = wave; seg < SEGS; seg += 16) {
      unsigned long long kv = sm.tk.skey[seg * 64 + lane];
#pragma unroll
      for (int k = 2; k <= 64; k <<= 1) {
#pragma unroll
        for (int j2 = k >> 1; j2 > 0; j2 >>= 1) {
          unsigned long long o = __shfl_xor(kv, j2, 64);
          bool lower = ((lane & j2) == 0);
          bool descblk = ((lane & k) == 0);
          bool wantmax = (descblk == lower);
          kv = (wantmax == (kv >= o)) ? kv : o;
        }
      }
      sm.tk.skey[seg * 64 + lane] = kv;
    }
    __syncthreads();
    // merge-rank: rank = pos-in-own-seg + sum over other segs of count(> key)
    for (int e = t; e < SEGS * 64; e += 1024) {
      unsigned long long key = sm.tk.skey[e];
      if (key == 0ull) continue;  // padding
      int seg = e >> 6;
      int rank = e & 63;
      for (int g = 0; g < SEGS; g++) {
        if (g == seg) continue;
        const unsigned long long* sp = &sm.tk.skey[g * 64];
        int lo = 0, hi = 64;
        while (lo < hi) {
          int mid = (lo + hi) >> 1;
          if (sp[mid] > key) lo = mid + 1; else hi = mid;
        }
        rank += lo;
      }
      if (rank < NSEL) feat_sel[s * NSEL + rank] = 16383 - (int)(key & 16383ull);
    }
    __syncthreads();   // topk done; LDS union reused below

    // ================= phase 2: qproj (slot B), all 1024 threads =================
    if (t < 256) sm.qp.srow[t] = slots[s * D_ + t];
    __syncthreads();
    {
      int o = t >> 2, part = t & 3;
      const float4* w4 = (const float4*)(ipw + (size_t)o * D_ + part * 64);
      float a = 0.f;
#pragma unroll
      for (int i = 0; i < 16; i++) {
        float4 w = w4[i];
        int d = part * 64 + i * 4;
        a += sm.qp.srow[d] * w.x + sm.qp.srow[d + 1] * w.y +
             sm.qp.srow[d + 2] * w.z + sm.qp.srow[d + 3] * w.w;
      }
      sm.qp.pq[t] = a;
    }
    __syncthreads();
    if (t < 256)
      sm.qp.qrow[t] = (sm.qp.pq[t * 4] + sm.qp.pq[t * 4 + 1] + sm.qp.pq[t * 4 + 2] +
                       sm.qp.pq[t * 4 + 3] + ipb[t]) * 0.17677669529663689f;
    __syncthreads();
    // qk[h][c]: 2048 dot-32s over 1024 threads (2 each)
    for (int e = t; e < 2048; e += 1024) {
      int h = e >> 8, c = e & 255;
      const float* wk = ipw + (size_t)(D_ + h * 32) * D_ + c;
      float a = 0.f;
#pragma unroll
      for (int k = 0; k < 32; k++) a += sm.qp.qrow[h * 32 + k] * wk[(size_t)k * D_];
      sm.qp.qkl[h][c] = a;
    }
    __syncthreads();
    if (t < 256) {
      float qs = 0.f;
#pragma unroll
      for (int h = 0; h < NHEAD; h++) qs += sm.qp.qkl[h][t];
      sm.qp.qsl[t] = qs;
    }
    if (t < NHEAD) {
      float a = 0.f;
      for (int e = 0; e < 32; e++) a += sm.qp.qrow[t * 32 + e] * ipb[D_ + t * 32 + e];
      qbk_g[s * NHEAD + t] = a;
    }
    __syncthreads();
    // qkb16[s][e], e=((kc*64+l)*8+j): col=l&15; k=kc*32+((l>>4)&3)*8+j.
    // cols 0-7 heads, col 8 qksum, 9-15 zero.
    for (int e = t; e < 4096; e += 1024) {
      int kc = e >> 9, l = (e >> 3) & 63, j = e & 7;
      int cc = l & 15, k = kc * 32 + ((l >> 4) & 3) * 8 + j;
      float v2 = (cc < NHEAD) ? sm.qp.qkl[cc][k] : ((cc == NHEAD) ? sm.qp.qsl[k] : 0.f);
      qkb16[(size_t)s * 4096 + e] = f2bf(v2);
    }
  } else {
    // ================= pack: kpf rows (1KB): [0:512) sigma-swizzled bf16(f+p),
    //                   [512:1024) linear bf16(f). 576 blocks, ~3.6 iters. =================
    int stride = PACKB * 1024;
    for (int u = (B - 256) * 1024 + t; u < HWN * BB * 32; u += stride) {
      int row = u >> 5, b2 = u & 31;
      int c8 = b2 << 3;
      const float4* f4 = (const float4*)(fsrc + (size_t)row * D_ + c8);
      const float4* p4 = (const float4*)(psrc + (size_t)row * D_ + c8);
      float4 a0 = f4[0], a1 = f4[1], b0 = p4[0], b1 = p4[1];
      uint4 kp, ff;
      kp.x = pk2(a0.x + b0.x, a0.y + b0.y);
      kp.y = pk2(a0.z + b0.z, a0.w + b0.w);
      kp.z = pk2(a1.x + b1.x, a1.y + b1.y);
      kp.w = pk2(a1.z + b1.z, a1.w + b1.w);
      ff.x = pk2(a0.x, a0.y); ff.y = pk2(a0.z, a0.w);
      ff.z = pk2(a1.x, a1.y); ff.w = pk2(a1.z, a1.w);
      int sig = row & 7;
      *(uint4*)(kpf + (size_t)row * 512 + ((b2 ^ sig) << 3)) = kp;
      *(uint4*)(kpf + (size_t)row * 512 + 256 + c8) = ff;
    }
  }
}

// ---------------- Kernel C (MFMA): aff via matrix cores + scalar PV (R15-R18, passing) ----------------
__global__ __launch_bounds__(256, 3) void aff_pv_mfma_kernel(
    const unsigned short* __restrict__ kpf,
    const unsigned short* __restrict__ qkb16,
    const int* __restrict__ batch_idx, const int* __restrict__ feat_sel,
    const float* __restrict__ qbk_g,
    float* __restrict__ fbar_part,    // [256][2][8][256]
    float* __restrict__ expsum_part,  // [256][2][8]
    float* __restrict__ stat_part,    // [256][2][2]
    float* __restrict__ aff2_g) {     // [256][768]
  __shared__ unsigned short kplds[4][4096];     // 32 KB: per-wave 16 rows x 512B (sigma layout)
  __shared__ unsigned short qkb[4096];          // 8 KB
  __shared__ float wlds[4][16][17];             // 4.3 KB
  __shared__ float fbar[NHEAD][D_];             // 8 KB
  __shared__ float a2buf[384];
  __shared__ int   sfsel[384];
  __shared__ float esums[4][NHEAD];
  __shared__ float sstat[4][2];
  __shared__ float qbkmean_s;

  int b = blockIdx.x, s = b >> 1, half = b & 1;
  int t = threadIdx.x, w = t >> 6, lane = t & 63;
  int bi = batch_idx[s];
  int col = lane & 15, quad = lane >> 4;

  {
    const uint4* src = (const uint4*)(qkb16 + (size_t)s * 4096);
    ((uint4*)qkb)[t] = src[t];
    ((uint4*)qkb)[t + 256] = src[t + 256];
  }
  for (int i = t; i < 384; i += 256) sfsel[i] = feat_sel[s * NSEL + half + 2 * i];
  for (int i = t; i < NHEAD * D_; i += 256) ((float*)fbar)[i] = 0.f;
  if (t == 0) {
    float m = 0.f;
    for (int h = 0; h < NHEAD; h++) m += qbk_g[s * NHEAD + h];
    qbkmean_s = m * 0.125f;
  }
  __syncthreads();

  unsigned short* kslot = &kplds[w][0];
  float acc[NHEAD][4];
#pragma unroll
  for (int h = 0; h < NHEAD; h++)
#pragma unroll
    for (int c = 0; c < 4; c++) acc[h][c] = 0.f;
  float esum_acc = 0.f;  // valid on lanes with col<8 (head=col)

  // 8 paired GLD16: lanes 0-31 <- row 2p kp-half, lanes 32-63 <- row 2p+1 kp-half.
  auto ISSUE_KP = [&](int L) {
#pragma unroll
    for (int p = 0; p < 8; p++) {
      int r0 = sfsel[L + 2 * p], r1 = sfsel[L + 2 * p + 1];
      unsigned ridx = (unsigned)((lane < 32 ? r0 : r1) * BB + bi);
      const unsigned short* src = kpf + (size_t)ridx * 512 + (lane & 31) * 8;
      GLD16(src, kslot + p * 512);
    }
  };

  ISSUE_KP(w * 64);  // prologue: tile 0
#pragma unroll 1
  for (int i = 0; i < 6; i++) {
    int L = (i < 4) ? (w * 64 + i * 16) : (256 + w * 32 + (i - 4) * 16);
    asm volatile("s_waitcnt vmcnt(0)" ::: "memory");  // tile i's 8 DMAs landed
    bool pos = (i < 4);
    uint2 fu[16];
    if (pos) {
#pragma unroll
      for (int r = 0; r < 16; r++)
        fu[r] = *(const uint2*)(kpf + (size_t)((unsigned)sfsel[L + r] * BB + bi) * 512 +
                                256 + lane * 4);
    }
    // A-frags: row col, k-block (kc*4+quad) xor sigma(row)
    unsigned sig = ((unsigned)sfsel[L + col] * BB + bi) & 7u;
    short8v afr[8];
#pragma unroll
    for (int kc = 0; kc < 8; kc++) {
      unsigned blk = ((unsigned)(kc * 4 + quad)) ^ sig;
      afr[kc] = *(const short8v*)(kslot + col * 256 + blk * 8);
    }
    asm volatile("s_waitcnt lgkmcnt(0)" ::: "memory");  // A reads done before slot reuse
    __builtin_amdgcn_sched_barrier(0);
    if (i < 5) {
      int Ln = (i < 3) ? (w * 64 + (i + 1) * 16) : (256 + w * 32 + (i - 3) * 16);
      ISSUE_KP(Ln);
    }
    float4v c = {0.f, 0.f, 0.f, 0.f};
#pragma unroll
    for (int kc = 0; kc < 8; kc++) {
      short8v bfr = *(const short8v*)&qkb[(kc * 64 + lane) * 8];
      c = __builtin_amdgcn_mfma_f32_16x16x32_bf16(afr[kc], bfr, c, 0, 0, 0);
    }
    // C: row n = quad*4+j (local row L+n), col: 0-7 heads, 8 = qksum-dot
    if (pos) {
      if (col < NHEAD) {
        float e0 = __expf(c[0]), e1 = __expf(c[1]), e2 = __expf(c[2]), e3 = __expf(c[3]);
        esum_acc += e0 + e1 + e2 + e3;
        wlds[w][quad * 4 + 0][col] = e0;
        wlds[w][quad * 4 + 1][col] = e1;
        wlds[w][quad * 4 + 2][col] = e2;
        wlds[w][quad * 4 + 3][col] = e3;
      } else if (col == NHEAD) {
        float qm = qbkmean_s;
#pragma unroll
        for (int j = 0; j < 4; j++) a2buf[L + quad * 4 + j] = c[j] * 0.125f + qm;
      }
      asm volatile("s_waitcnt lgkmcnt(0)" ::: "memory");  // wlds writes visible in-wave
      __builtin_amdgcn_sched_barrier(0);
#pragma unroll
      for (int r = 0; r < 16; r++) {
        const float4 w0 = *(const float4*)&wlds[w][r][0];
        const float4 w1 = *(const float4*)&wlds[w][r][4];
        float f0 = BFLO(fu[r].x), f1 = BFHI(fu[r].x), f2 = BFLO(fu[r].y), f3 = BFHI(fu[r].y);
        acc[0][0] += w0.x * f0; acc[0][1] += w0.x * f1; acc[0][2] += w0.x * f2; acc[0][3] += w0.x * f3;
        acc[1][0] += w0.y * f0; acc[1][1] += w0.y * f1; acc[1][2] += w0.y * f2; acc[1][3] += w0.y * f3;
        acc[2][0] += w0.z * f0; acc[2][1] += w0.z * f1; acc[2][2] += w0.z * f2; acc[2][3] += w0.z * f3;
        acc[3][0] += w0.w * f0; acc[3][1] += w0.w * f1; acc[3][2] += w0.w * f2; acc[3][3] += w0.w * f3;
        acc[4][0] += w1.x * f0; acc[4][1] += w1.x * f1; acc[4][2] += w1.x * f2; acc[4][3] += w1.x * f3;
        acc[5][0] += w1.y * f0; acc[5][1] += w1.y * f1; acc[5][2] += w1.y * f2; acc[5][3] += w1.y * f3;
        acc[6][0] += w1.z * f0; acc[6][1] += w1.z * f1; acc[6][2] += w1.z * f2; acc[6][3] += w1.z * f3;
        acc[7][0] += w1.w * f0; acc[7][1] += w1.w * f1; acc[7][2] += w1.w * f2; acc[7][3] += w1.w * f3;
      }
    } else {
      if (col == NHEAD) {
        float qm = qbkmean_s;
#pragma unroll
        for (int j = 0; j < 4; j++) a2buf[L + quad * 4 + j] = c[j] * 0.125f + qm;
      }
    }
  }

  // esum: combine quads (lanes h, h+16, h+32, h+48 all have col==h for h<8)
  esum_acc += __shfl_xor(esum_acc, 16, 64);
  esum_acc += __shfl_xor(esum_acc, 32, 64);
  if (lane < NHEAD) esums[w][lane] = esum_acc;
#pragma unroll
  for (int h = 0; h < NHEAD; h++) {
    atomicAdd(&fbar[h][lane * 4 + 0], acc[h][0]);
    atomicAdd(&fbar[h][lane * 4 + 1], acc[h][1]);
    atomicAdd(&fbar[h][lane * 4 + 2], acc[h][2]);
    atomicAdd(&fbar[h][lane * 4 + 3], acc[h][3]);
  }
  __syncthreads();

  {
    float v1 = a2buf[t];
    float v2 = (t < 128) ? a2buf[256 + t] : 0.f;
    float ls = v1 + v2, lq = v1 * v1 + v2 * v2;
#pragma unroll
    for (int off = 32; off >= 1; off >>= 1) { ls += __shfl_xor(ls, off, 64); lq += __shfl_xor(lq, off, 64); }
    if (lane == 0) { sstat[w][0] = ls; sstat[w][1] = lq; }
  }
  __syncthreads();
  if (t < NHEAD) {
    expsum_part[b * NHEAD + t] = esums[0][t] + esums[1][t] + esums[2][t] + esums[3][t];
  } else if (t == NHEAD) {
    stat_part[b * 2 + 0] = sstat[0][0] + sstat[1][0] + sstat[2][0] + sstat[3][0];
    stat_part[b * 2 + 1] = sstat[0][1] + sstat[1][1] + sstat[2][1] + sstat[3][1];
  }
  aff2_g[s * NSEL + half + 2 * t] = a2buf[t];
  if (t < 128) aff2_g[s * NSEL + half + 2 * (256 + t)] = a2buf[256 + t];
  ((float4*)(fbar_part + (size_t)b * 2048))[t] = ((float4*)fbar)[t];
  ((float4*)(fbar_part + (size_t)b * 2048))[t + 256] = ((float4*)fbar)[t + 256];
}

// ---------------- Kernel D: combine partials + Wv + out-proj + LN + norm_aff ----------------
__global__ __launch_bounds__(1024) void finish_kernel(
    const float* __restrict__ slots,
    const float* __restrict__ expsum_part, const float* __restrict__ stat_part,
    const float* __restrict__ aff2_g, const float* __restrict__ fbar_part,
    const float* __restrict__ ipw, const float* __restrict__ ipb,
    const float* __restrict__ wout, const float* __restrict__ bout,
    const float* __restrict__ lnw, const float* __restrict__ lnb,
    float* __restrict__ slots_new, float* __restrict__ norm_aff) {
  __shared__ float fbar[NHEAD][D_];
  __shared__ float srow[D_];
  __shared__ float outv[D_];
  __shared__ float pq[1024];
  __shared__ float redS[4], redQ[4];
  int s = blockIdx.x, t = threadIdx.x, wave = t >> 6, lane = t & 63;

  float st0 = stat_part[s * 4 + 0] + stat_part[s * 4 + 2];
  float st1 = stat_part[s * 4 + 1] + stat_part[s * 4 + 3];
  float mean_a = st0 * (1.0f / NSEL);
  float var_a = st1 * (1.0f / NSEL) - mean_a * mean_a;
  float rstd_a = rsqrtf(var_a + 1e-5f);
  if (t < NSEL) norm_aff[(size_t)t * NSLOT + s] = (aff2_g[s * NSEL + t] - mean_a) * rstd_a;

  if (t < 512) {
    int h = t >> 6;  // fbar layout [8][256]: 64 float4s per head
    float inv = 1.0f / (expsum_part[s * 16 + h] + expsum_part[s * 16 + 8 + h]);
    const float4 a = ((const float4*)(fbar_part + (size_t)s * 4096))[t];
    const float4 c = ((const float4*)(fbar_part + (size_t)s * 4096 + 2048))[t];
    float4 r;
    r.x = (a.x + c.x) * inv; r.y = (a.y + c.y) * inv;
    r.z = (a.z + c.z) * inv; r.w = (a.w + c.w) * inv;
    ((float4*)fbar)[t] = r;
  }
  if (t < 64) ((float4*)srow)[t] = ((const float4*)(slots + (size_t)s * D_))[t];
  __syncthreads();

  {
    int o = t >> 2, part = t & 3, h = o >> 5;
    const float4* wv = (const float4*)(ipw + (size_t)(2 * D_ + o) * D_ + part * 64);
    float a = 0.f;
#pragma unroll
    for (int i = 0; i < 16; i++) {
      float4 w = wv[i];
      int d = part * 64 + i * 4;
      a += fbar[h][d] * w.x + fbar[h][d + 1] * w.y + fbar[h][d + 2] * w.z + fbar[h][d + 3] * w.w;
    }
    pq[t] = a;
  }
  __syncthreads();
  if (t < D_)
    outv[t] = pq[t * 4] + pq[t * 4 + 1] + pq[t * 4 + 2] + pq[t * 4 + 3] + ipb[2 * D_ + t];
  __syncthreads();

  {
    int o = t >> 2, part = t & 3;
    const float4* w4 = (const float4*)(wout + (size_t)o * D_ + part * 64);
    float a = 0.f;
#pragma unroll
    for (int i = 0; i < 16; i++) {
      float4 w = w4[i];
      int d = part * 64 + i * 4;
      a += outv[d] * w.x + outv[d + 1] * w.y + outv[d + 2] * w.z + outv[d + 3] * w.w;
    }
    pq[t] = a;
  }
  __syncthreads();
  float v = 0.f;
  if (t < D_) {
    v = srow[t] + pq[t * 4] + pq[t * 4 + 1] + pq[t * 4 + 2] + pq[t * 4 + 3] + bout[t];
    float ls = v, lq = v * v;
#pragma unroll
    for (int off = 32; off >= 1; off >>= 1) { ls += __shfl_xor(ls, off, 64); lq += __shfl_xor(lq, off, 64); }
    if (lane == 0) { redS[wave] = ls; redQ[wave] = lq; }
  }
  __syncthreads();
  if (t < D_) {
    float tots = redS[0] + redS[1] + redS[2] + redS[3];
    float totq = redQ[0] + redQ[1] + redQ[2] + redQ[3];
    float mean = tots * (1.0f / D_);
    float var = totq * (1.0f / D_) - mean * mean;
    float rstd = rsqrtf(var + 1e-5f);
    slots_new[s * D_ + t] = (v - mean) * rstd * lnw[t] + lnb[t];
  }
}

extern "C" void kernel_launch(void* const* d_in, const int* in_sizes, int n_in,
                              void* d_out, int out_size, void* d_ws, size_t ws_size,
                              hipStream_t stream) {
  const float* slots    = (const float*)d_in[0];
  const float* features = (const float*)d_in[1];
  const float* posenc   = (const float*)d_in[2];
  const float* curio    = (const float*)d_in[3];
  const int*   batch_idx= (const int*)d_in[4];
  const float* ipw      = (const float*)d_in[5];
  const float* ipb      = (const float*)d_in[6];
  const float* wout     = (const float*)d_in[7];
  const float* bout     = (const float*)d_in[8];
  const float* lnw      = (const float*)d_in[9];
  const float* lnb      = (const float*)d_in[10];

  char* ws = (char*)d_ws;
  size_t off = 0;
  int*   feat_sel    = (int*)(ws + off);   off += 256 * 768 * 4;        // 786432
  float* qbk_g       = (float*)(ws + off); off += 256 * 8 * 4;          // 8192
  unsigned short* qkb16 = (unsigned short*)(ws + off); off += 256 * 4096 * 2; // 2097152
  float* fbar_part   = (float*)(ws + off); off += 256 * 2 * 8 * 256 * 4;// 4194304
  float* expsum_part = (float*)(ws + off); off += 256 * 2 * 8 * 4;      // 16384
  float* stat_part   = (float*)(ws + off); off += 256 * 2 * 2 * 4;      // 4096
  float* aff2_g      = (float*)(ws + off); off += 256 * 768 * 4;        // 786432
  size_t kpf_off = (off + 1023) & ~(size_t)1023;
  unsigned short* kpf = (unsigned short*)(ws + kpf_off);                // 67108864

  float* out_f = (float*)d_out;  // [0,65536) slots_new, [65536,262144) norm_aff

  prep_kernel<<<256 + PACKB, 1024, 0, stream>>>(curio, feat_sel, slots, ipw, ipb,
                                                qbk_g, qkb16, features, posenc, kpf);
  aff_pv_mfma_kernel<<<NSLOT * 2, 256, 0, stream>>>(kpf, qkb16, batch_idx, feat_sel,
                                                    qbk_g, fbar_part, expsum_part,
                                                    stat_part, aff2_g);
  finish_kernel<<<NSLOT, 1024, 0, stream>>>(slots, expsum_part, stat_part, aff2_g,
                                            fbar_part, ipw, ipb, wout, bout, lnw, lnb,
                                            out_f, out_f + 65536);
}

// Round 20
// 134.968 us; speedup vs baseline: 1.1123x; 1.0703x over previous
//
#include <hip/hip_runtime.h>
#include <math.h>

#define NSLOT 256
#define HWN   16384
#define D_    256
#define BB    4
#define NSEL  768
#define NPOS  512
#define NHEAD 8
#define SEGS  20                         // topk candidate capacity = 20*64 = 1280

typedef __attribute__((ext_vector_type(8))) short short8v;   // 8 bf16 (4 VGPRs)
typedef __attribute__((ext_vector_type(4))) float float4v;   // MFMA C/D

// global->LDS DMA: 16B per lane; LDS dest wave-uniform base; GLOBAL SOURCE PER-LANE.
#define GLD16(g, l)                                                        \
  __builtin_amdgcn_global_load_lds(                                        \
      (__attribute__((address_space(1))) void*)(g),                        \
      (__attribute__((address_space(3))) void*)(l), 16, 0, 0)

#define BFLO(u) __uint_as_float((u) << 16)
#define BFHI(u) __uint_as_float((u) & 0xffff0000u)

__device__ __forceinline__ unsigned short f2bf(float x) {   // RNE bf16
  unsigned u = __float_as_uint(x);
  unsigned r = u + 0x7fffu + ((u >> 16) & 1u);
  return (unsigned short)(r >> 16);
}
__device__ __forceinline__ unsigned int pk2(float a, float b) {
  return (unsigned)f2bf(a) | ((unsigned)f2bf(b) << 16);
}

// ---------------- Kernel PREP (R17 config, measured best: prep~80):
//   blocks 0-255: topk | 256-319: qproj x4 slots | 320-831: pack (512 blocks).
//   R20 tweak: topk curio passes vectorized to float4 (4x fewer load instrs).
union PrepSmem {
  struct {
    unsigned int hist[4096];
    unsigned int wsum[16];
    unsigned long long skey[SEGS * 64];
    int sBstar;
    unsigned int sCount;
  } tk;                                   // ~26.7 KB
  struct {
    float srow[4][D_];
    float qrow[4][D_];
    float qkl[4][NHEAD][D_];
    float qsl[4][D_];
  } qp;                                   // 44 KB
};

__global__ __launch_bounds__(1024) void prep_kernel(
    const float* __restrict__ curio, int* __restrict__ feat_sel,
    const float* __restrict__ slots, const float* __restrict__ ipw,
    const float* __restrict__ ipb, float* __restrict__ qbk_g,
    unsigned short* __restrict__ qkb16,
    const float* __restrict__ fsrc, const float* __restrict__ psrc,
    unsigned short* __restrict__ kpf) {
  __shared__ PrepSmem sm;
  int B = blockIdx.x;
  int t = threadIdx.x;

  if (B < 256) {
    // ---------------- topk: per-slot top-768 stable select ----------------
    int s = B;
    int wave = t >> 6, lane = t & 63;
    const float* row = curio + (size_t)s * HWN;

    for (int i = t; i < 4096; i += 1024) sm.tk.hist[i] = 0;
    if (t == 0) sm.tk.sCount = 0;
    __syncthreads();
    // histogram pass: float4 loads (HWN/4 = 4096 vec elems, 4 iters)
    for (int u = t; u < HWN / 4; u += 1024) {
      float4 v4 = *(const float4*)(row + u * 4);
      atomicAdd(&sm.tk.hist[__float_as_uint(v4.x) >> 18], 1u);
      atomicAdd(&sm.tk.hist[__float_as_uint(v4.y) >> 18], 1u);
      atomicAdd(&sm.tk.hist[__float_as_uint(v4.z) >> 18], 1u);
      atomicAdd(&sm.tk.hist[__float_as_uint(v4.w) >> 18], 1u);
    }
    __syncthreads();
    unsigned int cs = sm.tk.hist[t * 4] + sm.tk.hist[t * 4 + 1] +
                      sm.tk.hist[t * 4 + 2] + sm.tk.hist[t * 4 + 3];
    unsigned int v = cs;
#pragma unroll
    for (int off = 1; off < 64; off <<= 1) {
      unsigned int u = __shfl_down(v, off, 64);
      if (lane + off < 64) v += u;       // suffix over lanes >= lane (this wave)
    }
    if (lane == 0) sm.tk.wsum[wave] = v;
    __syncthreads();
    unsigned int above = 0;
    for (int w2 = wave + 1; w2 < 16; w2++) above += sm.tk.wsum[w2];
    unsigned int sufAfter = above + (v - cs);
    if (sufAfter < NSEL && sufAfter + cs >= NSEL) {
      unsigned int local = sufAfter;
      for (int b2 = t * 4 + 3; b2 >= t * 4; b2--) {
        unsigned int c = sm.tk.hist[b2];
        if (local + c >= NSEL) { sm.tk.sBstar = b2; break; }
        local += c;
      }
    }
    __syncthreads();
    int bstar = sm.tk.sBstar;
    // collect pass: float4 loads + ballot-aggregated atomics
    for (int u = t; u < HWN / 4; u += 1024) {
      float4 v4 = *(const float4*)(row + u * 4);
      unsigned int bb[4] = {__float_as_uint(v4.x), __float_as_uint(v4.y),
                            __float_as_uint(v4.z), __float_as_uint(v4.w)};
#pragma unroll
      for (int e = 0; e < 4; e++) {
        int j = u * 4 + e;
        bool cand = ((int)(bb[e] >> 18) >= bstar);
        unsigned long long mask = __ballot(cand);
        unsigned int base = 0;
        int lcnt = __popcll(mask);
        if (lane == 0 && lcnt) base = atomicAdd(&sm.tk.sCount, (unsigned)lcnt);
        base = __shfl(base, 0, 64);
        if (cand) {
          unsigned pos = base + __popcll(mask & ((1ull << lane) - 1ull));
          if (pos < SEGS * 64)
            sm.tk.skey[pos] = ((unsigned long long)bb[e] << 14) |
                              (unsigned long long)(16383 - j);
        }
      }
    }
    __syncthreads();
    unsigned int M = sm.tk.sCount;
    if (M > SEGS * 64) M = SEGS * 64;
    for (int i = t; i < SEGS * 64; i += 1024) if (i >= (int)M) sm.tk.skey[i] = 0ull;
    __syncthreads();
    // wave-local bitonic sort (descending) of each 64-seg, pure shuffles
    for (int seg = wave; seg < SEGS; seg += 16) {
      unsigned long long kv = sm.tk.skey[seg * 64 + lane];
#pragma unroll
      for (int k = 2; k <= 64; k <<= 1) {
#pragma unroll
        for (int j2 = k >> 1; j2 > 0; j2 >>= 1) {
          unsigned long long o = __shfl_xor(kv, j2, 64);
          bool lower = ((lane & j2) == 0);
          bool descblk = ((lane & k) == 0);
          bool wantmax = (descblk == lower);
          kv = (wantmax == (kv >= o)) ? kv : o;
        }
      }
      sm.tk.skey[seg * 64 + lane] = kv;
    }
    __syncthreads();
    // merge-rank: rank = pos-in-own-seg + sum over other segs of count(> key)
    for (int e = t; e < SEGS * 64; e += 1024) {
      unsigned long long key = sm.tk.skey[e];
      if (key == 0ull) continue;  // padding
      int seg = e >> 6;
      int rank = e & 63;
      for (int g = 0; g < SEGS; g++) {
        if (g == seg) continue;
        const unsigned long long* sp = &sm.tk.skey[g * 64];
        int lo = 0, hi = 64;
        while (lo < hi) {
          int mid = (lo + hi) >> 1;
          if (sp[mid] > key) lo = mid + 1; else hi = mid;
        }
        rank += lo;
      }
      if (rank < NSEL) feat_sel[s * NSEL + rank] = 16383 - (int)(key & 16383ull);
    }
  } else if (B < 320) {
    // ---------------- qproj: 4 slots per block (sub = t>>8) ----------------
    int sub = t >> 8, tt = t & 255;
    int s = (B - 256) * 4 + sub;
    float* srow = sm.qp.srow[sub];
    float* qrow = sm.qp.qrow[sub];
    float* qsl = sm.qp.qsl[sub];
    srow[tt] = slots[s * D_ + tt];
    __syncthreads();
    {
      const float* wq = ipw + (size_t)tt * D_;
      float acc = ipb[tt];
      for (int d = 0; d < D_; d++) acc += srow[d] * wq[d];
      qrow[tt] = acc * 0.17677669529663689f;  // 1/sqrt(32)
    }
    __syncthreads();
    float qsum = 0.f;
    for (int h = 0; h < NHEAD; h++) {
      const float* wkbase = ipw + (size_t)(D_ + h * 32) * D_ + tt;
      float a = 0.f;
      for (int e = 0; e < 32; e++) a += qrow[h * 32 + e] * wkbase[(size_t)e * D_];
      sm.qp.qkl[sub][h][tt] = a;
      qsum += a;
    }
    qsl[tt] = qsum;
    if (tt < NHEAD) {
      float a = 0.f;
      for (int e = 0; e < 32; e++) a += qrow[tt * 32 + e] * ipb[D_ + tt * 32 + e];
      qbk_g[s * NHEAD + tt] = a;
    }
    __syncthreads();
    // qkb16[s][e], e = ((kc*64+l)*8+j): B-frag order. col=l&15; k=kc*32+((l>>4)&3)*8+j.
    for (int i = 0; i < 16; i++) {
      int e = tt * 16 + i;
      int kc = e >> 9, l = (e >> 3) & 63, j = e & 7;
      int cc = l & 15, k = kc * 32 + ((l >> 4) & 3) * 8 + j;
      float v = (cc < NHEAD) ? sm.qp.qkl[sub][cc][k] : ((cc == NHEAD) ? qsl[k] : 0.f);
      qkb16[(size_t)s * 4096 + e] = f2bf(v);
    }
  } else {
    // ---------------- pack: kpf rows (1KB): [0:512) sigma-swizzled bf16(f+p),
    //                  [512:1024) linear bf16(f) ----------------
    int stride = 512 * 1024;
    for (int u = (B - 320) * 1024 + t; u < HWN * BB * 32; u += stride) {
      int row = u >> 5, b2 = u & 31;
      int c8 = b2 << 3;
      const float4* f4 = (const float4*)(fsrc + (size_t)row * D_ + c8);
      const float4* p4 = (const float4*)(psrc + (size_t)row * D_ + c8);
      float4 a0 = f4[0], a1 = f4[1], b0 = p4[0], b1 = p4[1];
      uint4 kp, ff;
      kp.x = pk2(a0.x + b0.x, a0.y + b0.y);
      kp.y = pk2(a0.z + b0.z, a0.w + b0.w);
      kp.z = pk2(a1.x + b1.x, a1.y + b1.y);
      kp.w = pk2(a1.z + b1.z, a1.w + b1.w);
      ff.x = pk2(a0.x, a0.y); ff.y = pk2(a0.z, a0.w);
      ff.z = pk2(a1.x, a1.y); ff.w = pk2(a1.z, a1.w);
      int sig = row & 7;
      *(uint4*)(kpf + (size_t)row * 512 + ((b2 ^ sig) << 3)) = kp;
      *(uint4*)(kpf + (size_t)row * 512 + 256 + c8) = ff;
    }
  }
}

// ---------------- Kernel C (MFMA): aff via matrix cores + scalar PV (R15-R19, passing) ----------------
__global__ __launch_bounds__(256, 3) void aff_pv_mfma_kernel(
    const unsigned short* __restrict__ kpf,
    const unsigned short* __restrict__ qkb16,
    const int* __restrict__ batch_idx, const int* __restrict__ feat_sel,
    const float* __restrict__ qbk_g,
    float* __restrict__ fbar_part,    // [256][2][8][256]
    float* __restrict__ expsum_part,  // [256][2][8]
    float* __restrict__ stat_part,    // [256][2][2]
    float* __restrict__ aff2_g) {     // [256][768]
  __shared__ unsigned short kplds[4][4096];     // 32 KB: per-wave 16 rows x 512B (sigma layout)
  __shared__ unsigned short qkb[4096];          // 8 KB
  __shared__ float wlds[4][16][17];             // 4.3 KB
  __shared__ float fbar[NHEAD][D_];             // 8 KB
  __shared__ float a2buf[384];
  __shared__ int   sfsel[384];
  __shared__ float esums[4][NHEAD];
  __shared__ float sstat[4][2];
  __shared__ float qbkmean_s;

  int b = blockIdx.x, s = b >> 1, half = b & 1;
  int t = threadIdx.x, w = t >> 6, lane = t & 63;
  int bi = batch_idx[s];
  int col = lane & 15, quad = lane >> 4;

  {
    const uint4* src = (const uint4*)(qkb16 + (size_t)s * 4096);
    ((uint4*)qkb)[t] = src[t];
    ((uint4*)qkb)[t + 256] = src[t + 256];
  }
  for (int i = t; i < 384; i += 256) sfsel[i] = feat_sel[s * NSEL + half + 2 * i];
  for (int i = t; i < NHEAD * D_; i += 256) ((float*)fbar)[i] = 0.f;
  if (t == 0) {
    float m = 0.f;
    for (int h = 0; h < NHEAD; h++) m += qbk_g[s * NHEAD + h];
    qbkmean_s = m * 0.125f;
  }
  __syncthreads();

  unsigned short* kslot = &kplds[w][0];
  float acc[NHEAD][4];
#pragma unroll
  for (int h = 0; h < NHEAD; h++)
#pragma unroll
    for (int c = 0; c < 4; c++) acc[h][c] = 0.f;
  float esum_acc = 0.f;  // valid on lanes with col<8 (head=col)

  // 8 paired GLD16: lanes 0-31 <- row 2p kp-half, lanes 32-63 <- row 2p+1 kp-half.
  auto ISSUE_KP = [&](int L) {
#pragma unroll
    for (int p = 0; p < 8; p++) {
      int r0 = sfsel[L + 2 * p], r1 = sfsel[L + 2 * p + 1];
      unsigned ridx = (unsigned)((lane < 32 ? r0 : r1) * BB + bi);
      const unsigned short* src = kpf + (size_t)ridx * 512 + (lane & 31) * 8;
      GLD16(src, kslot + p * 512);
    }
  };

  ISSUE_KP(w * 64);  // prologue: tile 0
#pragma unroll 1
  for (int i = 0; i < 6; i++) {
    int L = (i < 4) ? (w * 64 + i * 16) : (256 + w * 32 + (i - 4) * 16);
    asm volatile("s_waitcnt vmcnt(0)" ::: "memory");  // tile i's 8 DMAs landed
    bool pos = (i < 4);
    uint2 fu[16];
    if (pos) {
#pragma unroll
      for (int r = 0; r < 16; r++)
        fu[r] = *(const uint2*)(kpf + (size_t)((unsigned)sfsel[L + r] * BB + bi) * 512 +
                                256 + lane * 4);
    }
    // A-frags: row col, k-block (kc*4+quad) xor sigma(row)
    unsigned sig = ((unsigned)sfsel[L + col] * BB + bi) & 7u;
    short8v afr[8];
#pragma unroll
    for (int kc = 0; kc < 8; kc++) {
      unsigned blk = ((unsigned)(kc * 4 + quad)) ^ sig;
      afr[kc] = *(const short8v*)(kslot + col * 256 + blk * 8);
    }
    asm volatile("s_waitcnt lgkmcnt(0)" ::: "memory");  // A reads done before slot reuse
    __builtin_amdgcn_sched_barrier(0);
    if (i < 5) {
      int Ln = (i < 3) ? (w * 64 + (i + 1) * 16) : (256 + w * 32 + (i - 3) * 16);
      ISSUE_KP(Ln);
    }
    float4v c = {0.f, 0.f, 0.f, 0.f};
#pragma unroll
    for (int kc = 0; kc < 8; kc++) {
      short8v bfr = *(const short8v*)&qkb[(kc * 64 + lane) * 8];
      c = __builtin_amdgcn_mfma_f32_16x16x32_bf16(afr[kc], bfr, c, 0, 0, 0);
    }
    // C: row n = quad*4+j (local row L+n), col: 0-7 heads, 8 = qksum-dot
    if (pos) {
      if (col < NHEAD) {
        float e0 = __expf(c[0]), e1 = __expf(c[1]), e2 = __expf(c[2]), e3 = __expf(c[3]);
        esum_acc += e0 + e1 + e2 + e3;
        wlds[w][quad * 4 + 0][col] = e0;
        wlds[w][quad * 4 + 1][col] = e1;
        wlds[w][quad * 4 + 2][col] = e2;
        wlds[w][quad * 4 + 3][col] = e3;
      } else if (col == NHEAD) {
        float qm = qbkmean_s;
#pragma unroll
        for (int j = 0; j < 4; j++) a2buf[L + quad * 4 + j] = c[j] * 0.125f + qm;
      }
      asm volatile("s_waitcnt lgkmcnt(0)" ::: "memory");  // wlds writes visible in-wave
      __builtin_amdgcn_sched_barrier(0);
#pragma unroll
      for (int r = 0; r < 16; r++) {
        const float4 w0 = *(const float4*)&wlds[w][r][0];
        const float4 w1 = *(const float4*)&wlds[w][r][4];
        float f0 = BFLO(fu[r].x), f1 = BFHI(fu[r].x), f2 = BFLO(fu[r].y), f3 = BFHI(fu[r].y);
        acc[0][0] += w0.x * f0; acc[0][1] += w0.x * f1; acc[0][2] += w0.x * f2; acc[0][3] += w0.x * f3;
        acc[1][0] += w0.y * f0; acc[1][1] += w0.y * f1; acc[1][2] += w0.y * f2; acc[1][3] += w0.y * f3;
        acc[2][0] += w0.z * f0; acc[2][1] += w0.z * f1; acc[2][2] += w0.z * f2; acc[2][3] += w0.z * f3;
        acc[3][0] += w0.w * f0; acc[3][1] += w0.w * f1; acc[3][2] += w0.w * f2; acc[3][3] += w0.w * f3;
        acc[4][0] += w1.x * f0; acc[4][1] += w1.x * f1; acc[4][2] += w1.x * f2; acc[4][3] += w1.x * f3;
        acc[5][0] += w1.y * f0; acc[5][1] += w1.y * f1; acc[5][2] += w1.y * f2; acc[5][3] += w1.y * f3;
        acc[6][0] += w1.z * f0; acc[6][1] += w1.z * f1; acc[6][2] += w1.z * f2; acc[6][3] += w1.z * f3;
        acc[7][0] += w1.w * f0; acc[7][1] += w1.w * f1; acc[7][2] += w1.w * f2; acc[7][3] += w1.w * f3;
      }
    } else {
      if (col == NHEAD) {
        float qm = qbkmean_s;
#pragma unroll
        for (int j = 0; j < 4; j++) a2buf[L + quad * 4 + j] = c[j] * 0.125f + qm;
      }
    }
  }

  // esum: combine quads (lanes h, h+16, h+32, h+48 all have col==h for h<8)
  esum_acc += __shfl_xor(esum_acc, 16, 64);
  esum_acc += __shfl_xor(esum_acc, 32, 64);
  if (lane < NHEAD) esums[w][lane] = esum_acc;
#pragma unroll
  for (int h = 0; h < NHEAD; h++) {
    atomicAdd(&fbar[h][lane * 4 + 0], acc[h][0]);
    atomicAdd(&fbar[h][lane * 4 + 1], acc[h][1]);
    atomicAdd(&fbar[h][lane * 4 + 2], acc[h][2]);
    atomicAdd(&fbar[h][lane * 4 + 3], acc[h][3]);
  }
  __syncthreads();

  {
    float v1 = a2buf[t];
    float v2 = (t < 128) ? a2buf[256 + t] : 0.f;
    float ls = v1 + v2, lq = v1 * v1 + v2 * v2;
#pragma unroll
    for (int off = 32; off >= 1; off >>= 1) { ls += __shfl_xor(ls, off, 64); lq += __shfl_xor(lq, off, 64); }
    if (lane == 0) { sstat[w][0] = ls; sstat[w][1] = lq; }
  }
  __syncthreads();
  if (t < NHEAD) {
    expsum_part[b * NHEAD + t] = esums[0][t] + esums[1][t] + esums[2][t] + esums[3][t];
  } else if (t == NHEAD) {
    stat_part[b * 2 + 0] = sstat[0][0] + sstat[1][0] + sstat[2][0] + sstat[3][0];
    stat_part[b * 2 + 1] = sstat[0][1] + sstat[1][1] + sstat[2][1] + sstat[3][1];
  }
  aff2_g[s * NSEL + half + 2 * t] = a2buf[t];
  if (t < 128) aff2_g[s * NSEL + half + 2 * (256 + t)] = a2buf[256 + t];
  ((float4*)(fbar_part + (size_t)b * 2048))[t] = ((float4*)fbar)[t];
  ((float4*)(fbar_part + (size_t)b * 2048))[t + 256] = ((float4*)fbar)[t + 256];
}

// ---------------- Kernel D: combine partials + Wv + out-proj + LN + norm_aff ----------------
__global__ __launch_bounds__(1024) void finish_kernel(
    const float* __restrict__ slots,
    const float* __restrict__ expsum_part, const float* __restrict__ stat_part,
    const float* __restrict__ aff2_g, const float* __restrict__ fbar_part,
    const float* __restrict__ ipw, const float* __restrict__ ipb,
    const float* __restrict__ wout, const float* __restrict__ bout,
    const float* __restrict__ lnw, const float* __restrict__ lnb,
    float* __restrict__ slots_new, float* __restrict__ norm_aff) {
  __shared__ float fbar[NHEAD][D_];
  __shared__ float srow[D_];
  __shared__ float outv[D_];
  __shared__ float pq[1024];
  __shared__ float redS[4], redQ[4];
  int s = blockIdx.x, t = threadIdx.x, wave = t >> 6, lane = t & 63;

  float st0 = stat_part[s * 4 + 0] + stat_part[s * 4 + 2];
  float st1 = stat_part[s * 4 + 1] + stat_part[s * 4 + 3];
  float mean_a = st0 * (1.0f / NSEL);
  float var_a = st1 * (1.0f / NSEL) - mean_a * mean_a;
  float rstd_a = rsqrtf(var_a + 1e-5f);
  if (t < NSEL) norm_aff[(size_t)t * NSLOT + s] = (aff2_g[s * NSEL + t] - mean_a) * rstd_a;

  if (t < 512) {
    int h = t >> 6;  // fbar layout [8][256]: 64 float4s per head
    float inv = 1.0f / (expsum_part[s * 16 + h] + expsum_part[s * 16 + 8 + h]);
    const float4 a = ((const float4*)(fbar_part + (size_t)s * 4096))[t];
    const float4 c = ((const float4*)(fbar_part + (size_t)s * 4096 + 2048))[t];
    float4 r;
    r.x = (a.x + c.x) * inv; r.y = (a.y + c.y) * inv;
    r.z = (a.z + c.z) * inv; r.w = (a.w + c.w) * inv;
    ((float4*)fbar)[t] = r;
  }
  if (t < 64) ((float4*)srow)[t] = ((const float4*)(slots + (size_t)s * D_))[t];
  __syncthreads();

  {
    int o = t >> 2, part = t & 3, h = o >> 5;
    const float4* wv = (const float4*)(ipw + (size_t)(2 * D_ + o) * D_ + part * 64);
    float a = 0.f;
#pragma unroll
    for (int i = 0; i < 16; i++) {
      float4 w = wv[i];
      int d = part * 64 + i * 4;
      a += fbar[h][d] * w.x + fbar[h][d + 1] * w.y + fbar[h][d + 2] * w.z + fbar[h][d + 3] * w.w;
    }
    pq[t] = a;
  }
  __syncthreads();
  if (t < D_)
    outv[t] = pq[t * 4] + pq[t * 4 + 1] + pq[t * 4 + 2] + pq[t * 4 + 3] + ipb[2 * D_ + t];
  __syncthreads();

  {
    int o = t >> 2, part = t & 3;
    const float4* w4 = (const float4*)(wout + (size_t)o * D_ + part * 64);
    float a = 0.f;
#pragma unroll
    for (int i = 0; i < 16; i++) {
      float4 w = w4[i];
      int d = part * 64 + i * 4;
      a += outv[d] * w.x + outv[d + 1] * w.y + outv[d + 2] * w.z + outv[d + 3] * w.w;
    }
    pq[t] = a;
  }
  __syncthreads();
  float v = 0.f;
  if (t < D_) {
    v = srow[t] + pq[t * 4] + pq[t * 4 + 1] + pq[t * 4 + 2] + pq[t * 4 + 3] + bout[t];
    float ls = v, lq = v * v;
#pragma unroll
    for (int off = 32; off >= 1; off >>= 1) { ls += __shfl_xor(ls, off, 64); lq += __shfl_xor(lq, off, 64); }
    if (lane == 0) { redS[wave] = ls; redQ[wave] = lq; }
  }
  __syncthreads();
  if (t < D_) {
    float tots = redS[0] + redS[1] + redS[2] + redS[3];
    float totq = redQ[0] + redQ[1] + redQ[2] + redQ[3];
    float mean = tots * (1.0f / D_);
    float var = totq * (1.0f / D_) - mean * mean;
    float rstd = rsqrtf(var + 1e-5f);
    slots_new[s * D_ + t] = (v - mean) * rstd * lnw[t] + lnb[t];
  }
}

extern "C" void kernel_launch(void* const* d_in, const int* in_sizes, int n_in,
                              void* d_out, int out_size, void* d_ws, size_t ws_size,
                              hipStream_t stream) {
  const float* slots    = (const float*)d_in[0];
  const float* features = (const float*)d_in[1];
  const float* posenc   = (const float*)d_in[2];
  const float* curio    = (const float*)d_in[3];
  const int*   batch_idx= (const int*)d_in[4];
  const float* ipw      = (const float*)d_in[5];
  const float* ipb      = (const float*)d_in[6];
  const float* wout     = (const float*)d_in[7];
  const float* bout     = (const float*)d_in[8];
  const float* lnw      = (const float*)d_in[9];
  const float* lnb      = (const float*)d_in[10];

  char* ws = (char*)d_ws;
  size_t off = 0;
  int*   feat_sel    = (int*)(ws + off);   off += 256 * 768 * 4;        // 786432
  float* qbk_g       = (float*)(ws + off); off += 256 * 8 * 4;          // 8192
  unsigned short* qkb16 = (unsigned short*)(ws + off); off += 256 * 4096 * 2; // 2097152
  float* fbar_part   = (float*)(ws + off); off += 256 * 2 * 8 * 256 * 4;// 4194304
  float* expsum_part = (float*)(ws + off); off += 256 * 2 * 8 * 4;      // 16384
  float* stat_part   = (float*)(ws + off); off += 256 * 2 * 2 * 4;      // 4096
  float* aff2_g      = (float*)(ws + off); off += 256 * 768 * 4;        // 786432
  size_t kpf_off = (off + 1023) & ~(size_t)1023;
  unsigned short* kpf = (unsigned short*)(ws + kpf_off);                // 67108864

  float* out_f = (float*)d_out;  // [0,65536) slots_new, [65536,262144) norm_aff

  prep_kernel<<<832, 1024, 0, stream>>>(curio, feat_sel, slots, ipw, ipb,
                                        qbk_g, qkb16, features, posenc, kpf);
  aff_pv_mfma_kernel<<<NSLOT * 2, 256, 0, stream>>>(kpf, qkb16, batch_idx, feat_sel,
                                                    qbk_g, fbar_part, expsum_part,
                                                    stat_part, aff2_g);
  finish_kernel<<<NSLOT, 1024, 0, stream>>>(slots, expsum_part, stat_part, aff2_g,
                                            fbar_part, ipw, ipb, wout, bout, lnw, lnb,
                                            out_f, out_f + 65536);
}